// Round 7
// baseline (284.890 us; speedup 1.0000x reference)
//
#include <hip/hip_runtime.h>
#include <hip/hip_bf16.h>

// DTYPE FACTS (R2/R3): all float tensors FLOAT32 in device memory; output f32.
// Mask storage (bool8 / int32-or-f32 / bf16) probed at runtime (peer_mask all-true).
// HARNESS FLOOR (R4-R6): per-iteration 402MB d_ws poison fill (~58us @86% HBM)
// + d_in restores dominate the measured window; kernels are the ~60us slice.
// R6 LESSON: qproj/ffn are WEIGHT-READ-bound (each block reads full 256KB
// weight matrices). 8 rows/block, 192 blocks is the sweet spot; 4 rows/block
// doubled weight traffic and cost +17us. Do not shrink rows/block.

#define NU_ 500   // B=4, N=64, T=384, H=256, L=3 lags (1,5,21), TOPK=8

__device__ __forceinline__ bool mask_at(const void* p, long i, int mode){
  if (mode == 1) return ((const unsigned char*)p)[i] != 0;      // bool8
  if (mode == 2) return ((const unsigned short*)p)[i] != 0;     // bf16 bools
  return ((const unsigned int*)p)[i] != 0;                      // int32/f32 bools
}
__device__ __forceinline__ int lag_of(int l){ return (l == 0) ? 1 : ((l == 1) ? 5 : 21); }

// ---- kernel 1 (fused): blocks 0..191 -> qproj (8 rows) ; 192..195 -> prep
__global__ __launch_bounds__(256) void qproj_prep_kernel(
    const float* __restrict__ xg, const float* __restrict__ wq, const float* __restrict__ wqb,
    const float* __restrict__ wk, const float* __restrict__ wkb,
    const float* __restrict__ lrs, const void* __restrict__ pmask, const void* __restrict__ rmask,
    const int* __restrict__ target_id, const int* __restrict__ peer_id,
    const float* __restrict__ alpha_p,
    float* __restrict__ Qt, float* __restrict__ qb, float* __restrict__ prior)
{
  if (blockIdx.x >= 192){                      // ---- prep part ----
    const int b = blockIdx.x - 192;
    const int c = threadIdx.x;
    if (c >= 192) return;
    const unsigned char* pmB = (const unsigned char*)pmask;
    const unsigned char p0 = pmB[0], p1 = pmB[1];
    int mmode;
    if (p0 == 0x01u)      mmode = (p1 == 0x01u) ? 1 : 0;
    else if (p0 == 0x80u) mmode = 2;
    else                  mmode = 0;
    const int n = c / 3, l = c - n * 3;
    const int pid = peer_id[b * 64 + n];
    const int tgt = target_id[b];
    const long ridx = (long)l * (NU_*NU_) + (long)pid * NU_ + tgt;
    const bool ok = mask_at(pmask, b * 64 + n, mmode) && mask_at(rmask, ridx, mmode);
    prior[b * 192 + c] = ok ? alpha_p[0] * lrs[ridx] : -__builtin_inff();
    return;
  }
  // ---- qproj part: 8 rows per block (weight reuse x8) ----
  __shared__ __align__(16) float xs[8][256];
  __shared__ __align__(16) float qs[8][256];
  const int j = threadIdx.x;
  const int row0 = blockIdx.x * 8;
  #pragma unroll
  for (int r = 0; r < 8; ++r) xs[r][j] = xg[(long)(row0 + r) * 256 + j];
  __syncthreads();

  float acc[8];
  #pragma unroll
  for (int r = 0; r < 8; ++r) acc[r] = 0.f;
  const float4* wrow = (const float4*)(wq + (long)j * 256);
  for (int h8 = 0; h8 < 32; ++h8){
    float4 wa = wrow[h8 * 2], wb = wrow[h8 * 2 + 1];
    const int h = h8 * 8;
    #pragma unroll
    for (int r = 0; r < 8; ++r){
      const float* xr = &xs[r][h];   // uniform address -> LDS broadcast
      acc[r] += xr[0]*wa.x + xr[1]*wa.y + xr[2]*wa.z + xr[3]*wa.w
              + xr[4]*wb.x + xr[5]*wb.y + xr[6]*wb.z + xr[7]*wb.w;
    }
  }
  const float bq = wqb[j];
  #pragma unroll
  for (int r = 0; r < 8; ++r) qs[r][j] = acc[r] + bq;
  __syncthreads();

  float at[8];
  #pragma unroll
  for (int r = 0; r < 8; ++r) at[r] = 0.f;
  for (int h = 0; h < 256; ++h){
    const float w = wk[(long)h * 256 + j];     // coalesced across j
    #pragma unroll
    for (int r = 0; r < 8; ++r) at[r] += qs[r][h] * w;
  }
  #pragma unroll
  for (int r = 0; r < 8; ++r) Qt[(long)(row0 + r) * 256 + j] = at[r];

  const float bk = wkb[j];
  #pragma unroll
  for (int r = 0; r < 8; ++r) xs[r][j] = qs[r][j] * bk;
  __syncthreads();
  if (j < 8){
    float s = 0.f;
    for (int h = 0; h < 256; ++h) s += xs[j][h];
    qb[row0 + j] = s;
  }
}

// ---- kernel 2: compact valid candidates -> branch-free dot (8-lane groups)
//      -> top-8 -> softmax -> d = sum_k w_k*(now-lag). One block per (b,t).
__global__ __launch_bounds__(256) void attn_kernel(
    const float* __restrict__ peer_h, const float* __restrict__ Qt,
    const float* __restrict__ qbv, const float* __restrict__ prior,
    float* __restrict__ dvec, float* __restrict__ ssum)
{
  __shared__ __align__(16) float qt_s[288];   // padded: idx = h + 4*(h/32)
  __shared__ float pr_s[192];
  __shared__ float lg[192];     // compacted logits (slot-indexed)
  __shared__ int   ix_s[192];   // slot -> original candidate (1000+slot if empty)
  __shared__ int   wcnt[4];
  __shared__ int   seli[8];
  __shared__ float selw[8];
  __shared__ int   allinf_sh;
  const int bt = blockIdx.x;
  const int b = bt / 384, t = bt % 384;
  const int tid = threadIdx.x;
  const int lane = tid & 63, wvi = tid >> 6;
  const float NEG_INF = -__builtin_inff();

  qt_s[tid + ((tid >> 5) << 2)] = Qt[(long)bt * 256 + tid];
  bool valid = false;
  if (tid < 192){
    pr_s[tid] = prior[b * 192 + tid];
    lg[tid] = NEG_INF;
    ix_s[tid] = 1000 + tid;                   // empty-slot sentinel (big index)
    const int l = tid - (tid / 3) * 3;
    valid = (t >= lag_of(l)) && (pr_s[tid] > -3.0e38f);
  }
  // ordered compaction: per-wave ballot + prefix popcount (deterministic)
  const unsigned long long bal = __ballot(valid);
  if (lane == 0) wcnt[wvi] = __popcll(bal);
  __syncthreads();
  const int cnt = wcnt[0] + wcnt[1] + wcnt[2];   // wave 3 contributes none
  if (valid){
    int base = 0;
    for (int i = 0; i < wvi; ++i) base += wcnt[i];
    const int pos = base + __popcll(bal & ((1ULL << lane) - 1ULL));
    ix_s[pos] = tid;
  }
  __syncthreads();

  const float qb = qbv[bt];
  // 8-lane groups (32 groups); lane q owns Qt[32q .. 32q+32)
  const int group = tid >> 3, q = tid & 7;
  float qv[32];
  #pragma unroll
  for (int k = 0; k < 8; ++k){
    float4 f = *(const float4*)&qt_s[36 * q + 4 * k];  // pad spreads banks
    qv[4*k] = f.x; qv[4*k+1] = f.y; qv[4*k+2] = f.z; qv[4*k+3] = f.w;
  }

  // branch-free dot over compacted list (~38 valid of 192 typical)
  for (int i = group; i < cnt; i += 32){
    const int c = ix_s[i];
    const int n = c / 3, l = c - n * 3;
    const int tc = t - lag_of(l);             // valid by construction (>= 0)
    const float4* rp = (const float4*)(peer_h + (((long)(b*64 + n)) * 384 + tc) * 256);
    float p = 0.f;
    #pragma unroll
    for (int k = 0; k < 8; ++k){
      float4 u = rp[q * 8 + k];               // 128 B/lane, 1 KB per group
      p += u.x*qv[4*k] + u.y*qv[4*k+1] + u.z*qv[4*k+2] + u.w*qv[4*k+3];
    }
    #pragma unroll
    for (int off = 1; off < 8; off <<= 1) p += __shfl_xor(p, off);
    if (q == 0) lg[i] = (p + qb) * 0.0625f + pr_s[c];   // 1/sqrt(256)
  }
  __syncthreads();

  if (tid < 64){
    // top-8 of 192 slots; tie-break by lower ORIGINAL index (jax top_k order)
    float v0 = lg[lane], v1 = lg[lane + 64], v2 = lg[lane + 128];
    int   i0 = ix_s[lane], i1 = ix_s[lane + 64], i2 = ix_s[lane + 128];
    float sv[8]; int si[8];
    for (int k = 0; k < 8; ++k){
      float mv = v0; int mi = i0; int ms = 0;
      if (v1 > mv || (v1 == mv && i1 < mi)){ mv = v1; mi = i1; ms = 1; }
      if (v2 > mv || (v2 == mv && i2 < mi)){ mv = v2; mi = i2; ms = 2; }
      #pragma unroll
      for (int off = 32; off; off >>= 1){
        float ov = __shfl_xor(mv, off);
        int   oi = __shfl_xor(mi, off);
        int   os = __shfl_xor(ms, off);
        if (ov > mv || (ov == mv && oi < mi)){ mv = ov; mi = oi; ms = os; }
      }
      sv[k] = mv; si[k] = mi;
      if (mi == i0 && ms == 0)      v0 = NEG_INF;
      else if (mi == i1 && ms == 1) v1 = NEG_INF;
      else if (mi == i2 && ms == 2) v2 = NEG_INF;
    }
    const int allinf = (sv[0] == NEG_INF) ? 1 : 0;
    const float m = allinf ? -1e9f : sv[0];
    float e[8]; float tot = 0.f;
    #pragma unroll
    for (int k = 0; k < 8; ++k){
      const float s = (sv[k] == NEG_INF) ? -1e9f : sv[k];   // ref: -inf -> -1e9
      e[k] = expf(s - m);
      tot += e[k];
    }
    if (lane == 0){
      allinf_sh = allinf;
      const float inv = 1.f / tot;
      for (int k = 0; k < 8; ++k){
        seli[k] = si[k];
        selw[k] = allinf ? 0.f : e[k] * inv;
      }
    }
  }
  __syncthreads();

  // branch-free combine: w==0 nullifies empty/-inf picks; addresses clamped
  float acc = 0.f;
  const int h = tid;
  #pragma unroll
  for (int k = 0; k < 8; ++k){
    const float w = selw[k];
    const int c = min(seli[k], 191);          // sentinel 1000+slot -> safe row
    const int n = c / 3, l = c - n * 3;
    const int tc = max(t - lag_of(l), 0);
    const long base = ((long)(b*64 + n)) * 384;
    acc += w * (peer_h[(base + t ) * 256 + h]
              - peer_h[(base + tc) * 256 + h]);
  }
  dvec[(long)bt * 256 + h] = acc;
  if (tid == 0) ssum[bt] = allinf_sh ? 0.f : 1.f;
}

// ---- kernel 3: ll = d@wv^T + s*wv_b ; x = ll + f2(elu(f1(ll))) ; LN ------
// 8 rows per block, 192 blocks (weight reuse x8 — see R6 lesson).
__global__ __launch_bounds__(256) void ffn_kernel(
    const float* __restrict__ dv, const float* __restrict__ sv,
    const float* __restrict__ wv, const float* __restrict__ wvb,
    const float* __restrict__ f1, const float* __restrict__ f1b,
    const float* __restrict__ f2, const float* __restrict__ f2b,
    const float* __restrict__ lng, const float* __restrict__ lnb,
    float* __restrict__ out)
{
  __shared__ __align__(16) float ds[8][256];
  __shared__ __align__(16) float ys[8][256];
  __shared__ float mu_s[8], rs_s[8];
  const int j = threadIdx.x;
  const int row0 = blockIdx.x * 8;
  #pragma unroll
  for (int r = 0; r < 8; ++r) ds[r][j] = dv[(long)(row0 + r) * 256 + j];
  __syncthreads();

  float ll[8];
  {
    #pragma unroll
    for (int r = 0; r < 8; ++r) ll[r] = 0.f;
    const float4* wrow = (const float4*)(wv + (long)j * 256);
    for (int h8 = 0; h8 < 32; ++h8){
      float4 wa = wrow[h8 * 2], wb = wrow[h8 * 2 + 1];
      const int h = h8 * 8;
      #pragma unroll
      for (int r = 0; r < 8; ++r){
        const float* xr = &ds[r][h];
        ll[r] += xr[0]*wa.x + xr[1]*wa.y + xr[2]*wa.z + xr[3]*wa.w
               + xr[4]*wb.x + xr[5]*wb.y + xr[6]*wb.z + xr[7]*wb.w;
      }
    }
    const float bv = wvb[j];
    #pragma unroll
    for (int r = 0; r < 8; ++r) ll[r] += sv[row0 + r] * bv;
  }
  #pragma unroll
  for (int r = 0; r < 8; ++r) ys[r][j] = ll[r];
  __syncthreads();

  {
    float a[8];
    #pragma unroll
    for (int r = 0; r < 8; ++r) a[r] = 0.f;
    const float4* wrow = (const float4*)(f1 + (long)j * 256);
    for (int h8 = 0; h8 < 32; ++h8){
      float4 wa = wrow[h8 * 2], wb = wrow[h8 * 2 + 1];
      const int h = h8 * 8;
      #pragma unroll
      for (int r = 0; r < 8; ++r){
        const float* xr = &ys[r][h];
        a[r] += xr[0]*wa.x + xr[1]*wa.y + xr[2]*wa.z + xr[3]*wa.w
              + xr[4]*wb.x + xr[5]*wb.y + xr[6]*wb.z + xr[7]*wb.w;
      }
    }
    const float b1 = f1b[j];
    #pragma unroll
    for (int r = 0; r < 8; ++r){
      const float x = a[r] + b1;
      ds[r][j] = (x > 0.f) ? x : expm1f(x);   // jax.nn.elu
    }
  }
  __syncthreads();

  float xv[8];
  {
    float a[8];
    #pragma unroll
    for (int r = 0; r < 8; ++r) a[r] = 0.f;
    const float4* wrow = (const float4*)(f2 + (long)j * 256);
    for (int h8 = 0; h8 < 32; ++h8){
      float4 wa = wrow[h8 * 2], wb = wrow[h8 * 2 + 1];
      const int h = h8 * 8;
      #pragma unroll
      for (int r = 0; r < 8; ++r){
        const float* xr = &ds[r][h];
        a[r] += xr[0]*wa.x + xr[1]*wa.y + xr[2]*wa.z + xr[3]*wa.w
              + xr[4]*wb.x + xr[5]*wb.y + xr[6]*wb.z + xr[7]*wb.w;
      }
    }
    const float b2_ = f2b[j];
    #pragma unroll
    for (int r = 0; r < 8; ++r) xv[r] = ll[r] + a[r] + b2_;
  }
  #pragma unroll
  for (int r = 0; r < 8; ++r) ys[r][j] = xv[r];
  __syncthreads();

  {
    const int lane = j & 63, wvi = j >> 6;
    for (int rr = 0; rr < 2; ++rr){
      const int r = wvi * 2 + rr;
      float s = 0.f, qq = 0.f;
      for (int p = lane; p < 256; p += 64){ const float x = ys[r][p]; s += x; qq += x * x; }
      #pragma unroll
      for (int off = 32; off; off >>= 1){ s += __shfl_xor(s, off); qq += __shfl_xor(qq, off); }
      if (lane == 0){
        const float mu = s * (1.f/256.f);
        const float var = qq * (1.f/256.f) - mu * mu;
        mu_s[r] = mu; rs_s[r] = rsqrtf(var + 1e-5f);
      }
    }
  }
  __syncthreads();
  const float gj = lng[j], bj = lnb[j];
  #pragma unroll
  for (int r = 0; r < 8; ++r){
    const float o = (ys[r][j] - mu_s[r]) * rs_s[r] * gj + bj;
    out[(long)(row0 + r) * 256 + j] = o;
  }
}

extern "C" void kernel_launch(void* const* d_in, const int* in_sizes, int n_in,
                              void* d_out, int out_size, void* d_ws, size_t ws_size,
                              hipStream_t stream)
{
  (void)in_sizes; (void)n_in; (void)out_size; (void)ws_size;
  const float* target_h = (const float*)d_in[0];
  const float* peer_h   = (const float*)d_in[1];
  const float* wq_w = (const float*)d_in[2];  const float* wq_b = (const float*)d_in[3];
  const float* wk_w = (const float*)d_in[4];  const float* wk_b = (const float*)d_in[5];
  const float* wv_w = (const float*)d_in[6];  const float* wv_b = (const float*)d_in[7];
  const float* f1_w = (const float*)d_in[8];  const float* f1_b = (const float*)d_in[9];
  const float* f2_w = (const float*)d_in[10]; const float* f2_b = (const float*)d_in[11];
  const float* ln_g = (const float*)d_in[12]; const float* ln_b = (const float*)d_in[13];
  const float* alpha = (const float*)d_in[14];
  const float* lrs  = (const float*)d_in[15];
  const void* pmask = d_in[16];
  const void* rmask = d_in[17];
  const int* target_id = (const int*)d_in[18];
  const int* peer_id   = (const int*)d_in[19];

  // ws layout (f32): prior[4*192] | Qt[1536*256] | qb[1536] | d[1536*256] | s[1536]
  float* prior = (float*)d_ws;
  float* Qt    = prior + 4 * 192;
  float* qb    = Qt + 393216;
  float* dvec  = qb + 1536;
  float* ssum  = dvec + 393216;

  qproj_prep_kernel<<<196, 256, 0, stream>>>(target_h, wq_w, wq_b, wk_w, wk_b,
      lrs, pmask, rmask, target_id, peer_id, alpha, Qt, qb, prior);
  attn_kernel<<<1536, 256, 0, stream>>>(peer_h, Qt, qb, prior, dvec, ssum);
  ffn_kernel<<<192, 256, 0, stream>>>(dvec, ssum, wv_w, wv_b, f1_w, f1_b,
                                      f2_w, f2_b, ln_g, ln_b, (float*)d_out);
}

// Round 8
// 263.084 us; speedup vs baseline: 1.0829x; 1.0829x over previous
//
#include <hip/hip_runtime.h>
#include <hip/hip_bf16.h>

// DTYPE FACTS (R2/R3): all float tensors FLOAT32 in device memory; output f32.
// Mask storage (bool8 / int32-or-f32 / bf16) probed at runtime (peer_mask all-true).
// HARNESS FLOOR (R4-R7): per-iteration 402MB d_ws poison fill (~58us @86% HBM)
// + d_in restores dominate the measured window.
// CONFIG FACTS (R5/R6/R7 A/B): attn MUST use 16-lane groups (8-lane groups with
// 128B-stride loads + qv[32] cost +20us — R7). qproj/ffn rows/block is ~neutral
// (R6 vs R7); 8-row keeps weight reuse x8. This file == R5 (best: 264.5us).

#define NU_ 500   // B=4, N=64, T=384, H=256, L=3 lags (1,5,21), TOPK=8

__device__ __forceinline__ bool mask_at(const void* p, long i, int mode){
  if (mode == 1) return ((const unsigned char*)p)[i] != 0;      // bool8
  if (mode == 2) return ((const unsigned short*)p)[i] != 0;     // bf16 bools
  return ((const unsigned int*)p)[i] != 0;                      // int32/f32 bools
}
__device__ __forceinline__ int lag_of(int l){ return (l == 0) ? 1 : ((l == 1) ? 5 : 21); }

// ---- kernel 1 (fused): blocks 0..191 -> qproj (8 rows) ; 192..195 -> prep
__global__ __launch_bounds__(256) void qproj_prep_kernel(
    const float* __restrict__ xg, const float* __restrict__ wq, const float* __restrict__ wqb,
    const float* __restrict__ wk, const float* __restrict__ wkb,
    const float* __restrict__ lrs, const void* __restrict__ pmask, const void* __restrict__ rmask,
    const int* __restrict__ target_id, const int* __restrict__ peer_id,
    const float* __restrict__ alpha_p,
    float* __restrict__ Qt, float* __restrict__ qb, float* __restrict__ prior)
{
  if (blockIdx.x >= 192){                      // ---- prep part ----
    const int b = blockIdx.x - 192;
    const int c = threadIdx.x;
    if (c >= 192) return;
    const unsigned char* pmB = (const unsigned char*)pmask;
    const unsigned char p0 = pmB[0], p1 = pmB[1];
    int mmode;
    if (p0 == 0x01u)      mmode = (p1 == 0x01u) ? 1 : 0;
    else if (p0 == 0x80u) mmode = 2;
    else                  mmode = 0;
    const int n = c / 3, l = c - n * 3;
    const int pid = peer_id[b * 64 + n];
    const int tgt = target_id[b];
    const long ridx = (long)l * (NU_*NU_) + (long)pid * NU_ + tgt;
    const bool ok = mask_at(pmask, b * 64 + n, mmode) && mask_at(rmask, ridx, mmode);
    prior[b * 192 + c] = ok ? alpha_p[0] * lrs[ridx] : -__builtin_inff();
    return;
  }
  // ---- qproj part: 8 rows per block (weight reuse x8) ----
  __shared__ __align__(16) float xs[8][256];
  __shared__ __align__(16) float qs[8][256];
  const int j = threadIdx.x;
  const int row0 = blockIdx.x * 8;
  #pragma unroll
  for (int r = 0; r < 8; ++r) xs[r][j] = xg[(long)(row0 + r) * 256 + j];
  __syncthreads();

  float acc[8];
  #pragma unroll
  for (int r = 0; r < 8; ++r) acc[r] = 0.f;
  const float4* wrow = (const float4*)(wq + (long)j * 256);
  for (int h8 = 0; h8 < 32; ++h8){
    float4 wa = wrow[h8 * 2], wb = wrow[h8 * 2 + 1];
    const int h = h8 * 8;
    #pragma unroll
    for (int r = 0; r < 8; ++r){
      const float* xr = &xs[r][h];   // uniform address -> LDS broadcast
      acc[r] += xr[0]*wa.x + xr[1]*wa.y + xr[2]*wa.z + xr[3]*wa.w
              + xr[4]*wb.x + xr[5]*wb.y + xr[6]*wb.z + xr[7]*wb.w;
    }
  }
  const float bq = wqb[j];
  #pragma unroll
  for (int r = 0; r < 8; ++r) qs[r][j] = acc[r] + bq;
  __syncthreads();

  float at[8];
  #pragma unroll
  for (int r = 0; r < 8; ++r) at[r] = 0.f;
  for (int h = 0; h < 256; ++h){
    const float w = wk[(long)h * 256 + j];     // coalesced across j
    #pragma unroll
    for (int r = 0; r < 8; ++r) at[r] += qs[r][h] * w;
  }
  #pragma unroll
  for (int r = 0; r < 8; ++r) Qt[(long)(row0 + r) * 256 + j] = at[r];

  const float bk = wkb[j];
  #pragma unroll
  for (int r = 0; r < 8; ++r) xs[r][j] = qs[r][j] * bk;
  __syncthreads();
  if (j < 8){
    float s = 0.f;
    for (int h = 0; h < 256; ++h) s += xs[j][h];
    qb[row0 + j] = s;
  }
}

// ---- kernel 2: compact valid candidates -> branch-free dot (16-lane groups)
//      -> top-8 -> softmax -> d = sum_k w_k*(now-lag). One block per (b,t).
__global__ __launch_bounds__(256) void attn_kernel(
    const float* __restrict__ peer_h, const float* __restrict__ Qt,
    const float* __restrict__ qbv, const float* __restrict__ prior,
    float* __restrict__ dvec, float* __restrict__ ssum)
{
  __shared__ __align__(16) float qt_s[256];
  __shared__ float pr_s[192];
  __shared__ float lg[192];     // compacted logits (slot-indexed)
  __shared__ int   ix_s[192];   // slot -> original candidate (1000+slot if empty)
  __shared__ int   wcnt[4];
  __shared__ int   seli[8];
  __shared__ float selw[8];
  __shared__ int   allinf_sh;
  const int bt = blockIdx.x;
  const int b = bt / 384, t = bt % 384;
  const int tid = threadIdx.x;
  const int lane = tid & 63, wvi = tid >> 6;
  const float NEG_INF = -__builtin_inff();

  qt_s[tid] = Qt[(long)bt * 256 + tid];
  bool valid = false;
  if (tid < 192){
    pr_s[tid] = prior[b * 192 + tid];
    lg[tid] = NEG_INF;
    ix_s[tid] = 1000 + tid;                   // empty-slot sentinel (big index)
    const int l = tid - (tid / 3) * 3;
    valid = (t >= lag_of(l)) && (pr_s[tid] > -3.0e38f);
  }
  // ordered compaction: per-wave ballot + prefix popcount (deterministic)
  const unsigned long long bal = __ballot(valid);
  if (lane == 0) wcnt[wvi] = __popcll(bal);
  __syncthreads();
  const int cnt = wcnt[0] + wcnt[1] + wcnt[2];   // wave 3 contributes none
  if (valid){
    int base = 0;
    for (int i = 0; i < wvi; ++i) base += wcnt[i];
    const int pos = base + __popcll(bal & ((1ULL << lane) - 1ULL));
    ix_s[pos] = tid;
  }
  __syncthreads();

  const float qb = qbv[bt];
  // 16-lane groups; lane q owns Qt[16q .. 16q+16)
  const int group = tid >> 4, q = tid & 15;
  float qv[16];
  #pragma unroll
  for (int i = 0; i < 4; ++i){
    float4 f = *(const float4*)&qt_s[q * 16 + i * 4];
    qv[i*4] = f.x; qv[i*4+1] = f.y; qv[i*4+2] = f.z; qv[i*4+3] = f.w;
  }

  // branch-free dot over compacted list (~38 valid of 192 typical)
  for (int i = group; i < cnt; i += 16){
    const int c = ix_s[i];
    const int n = c / 3, l = c - n * 3;
    const int tc = t - lag_of(l);             // valid by construction (>= 0)
    const float4* rp = (const float4*)(peer_h + (((long)(b*64 + n)) * 384 + tc) * 256);
    float4 u0 = rp[q*4], u1 = rp[q*4+1], u2 = rp[q*4+2], u3 = rp[q*4+3];
    float p = u0.x*qv[0] + u0.y*qv[1] + u0.z*qv[2] + u0.w*qv[3]
            + u1.x*qv[4] + u1.y*qv[5] + u1.z*qv[6] + u1.w*qv[7]
            + u2.x*qv[8] + u2.y*qv[9] + u2.z*qv[10]+ u2.w*qv[11]
            + u3.x*qv[12]+ u3.y*qv[13]+ u3.z*qv[14]+ u3.w*qv[15];
    #pragma unroll
    for (int off = 1; off < 16; off <<= 1) p += __shfl_xor(p, off);
    if (q == 0) lg[i] = (p + qb) * 0.0625f + pr_s[c];   // 1/sqrt(256)
  }
  __syncthreads();

  if (tid < 64){
    // top-8 of 192 slots; tie-break by lower ORIGINAL index (jax top_k order)
    float v0 = lg[lane], v1 = lg[lane + 64], v2 = lg[lane + 128];
    int   i0 = ix_s[lane], i1 = ix_s[lane + 64], i2 = ix_s[lane + 128];
    float sv[8]; int si[8];
    for (int k = 0; k < 8; ++k){
      float mv = v0; int mi = i0; int ms = 0;
      if (v1 > mv || (v1 == mv && i1 < mi)){ mv = v1; mi = i1; ms = 1; }
      if (v2 > mv || (v2 == mv && i2 < mi)){ mv = v2; mi = i2; ms = 2; }
      #pragma unroll
      for (int off = 32; off; off >>= 1){
        float ov = __shfl_xor(mv, off);
        int   oi = __shfl_xor(mi, off);
        int   os = __shfl_xor(ms, off);
        if (ov > mv || (ov == mv && oi < mi)){ mv = ov; mi = oi; ms = os; }
      }
      sv[k] = mv; si[k] = mi;
      if (mi == i0 && ms == 0)      v0 = NEG_INF;
      else if (mi == i1 && ms == 1) v1 = NEG_INF;
      else if (mi == i2 && ms == 2) v2 = NEG_INF;
    }
    const int allinf = (sv[0] == NEG_INF) ? 1 : 0;
    const float m = allinf ? -1e9f : sv[0];
    float e[8]; float tot = 0.f;
    #pragma unroll
    for (int k = 0; k < 8; ++k){
      const float s = (sv[k] == NEG_INF) ? -1e9f : sv[k];   // ref: -inf -> -1e9
      e[k] = expf(s - m);
      tot += e[k];
    }
    if (lane == 0){
      allinf_sh = allinf;
      const float inv = 1.f / tot;
      for (int k = 0; k < 8; ++k){
        seli[k] = si[k];
        selw[k] = allinf ? 0.f : e[k] * inv;
      }
    }
  }
  __syncthreads();

  // branch-free combine: w==0 nullifies empty/-inf picks; addresses clamped
  float acc = 0.f;
  const int h = tid;
  #pragma unroll
  for (int k = 0; k < 8; ++k){
    const float w = selw[k];
    const int c = min(seli[k], 191);          // sentinel 1000+slot -> safe row
    const int n = c / 3, l = c - n * 3;
    const int tc = max(t - lag_of(l), 0);
    const long base = ((long)(b*64 + n)) * 384;
    acc += w * (peer_h[(base + t ) * 256 + h]
              - peer_h[(base + tc) * 256 + h]);
  }
  dvec[(long)bt * 256 + h] = acc;
  if (tid == 0) ssum[bt] = allinf_sh ? 0.f : 1.f;
}

// ---- kernel 3: ll = d@wv^T + s*wv_b ; x = ll + f2(elu(f1(ll))) ; LN ------
__global__ __launch_bounds__(256) void ffn_kernel(
    const float* __restrict__ dv, const float* __restrict__ sv,
    const float* __restrict__ wv, const float* __restrict__ wvb,
    const float* __restrict__ f1, const float* __restrict__ f1b,
    const float* __restrict__ f2, const float* __restrict__ f2b,
    const float* __restrict__ lng, const float* __restrict__ lnb,
    float* __restrict__ out)
{
  __shared__ __align__(16) float ds[8][256];
  __shared__ __align__(16) float ys[8][256];
  __shared__ float mu_s[8], rs_s[8];
  const int j = threadIdx.x;
  const int row0 = blockIdx.x * 8;
  #pragma unroll
  for (int r = 0; r < 8; ++r) ds[r][j] = dv[(long)(row0 + r) * 256 + j];
  __syncthreads();

  float ll[8];
  {
    #pragma unroll
    for (int r = 0; r < 8; ++r) ll[r] = 0.f;
    const float4* wrow = (const float4*)(wv + (long)j * 256);
    for (int h8 = 0; h8 < 32; ++h8){
      float4 wa = wrow[h8 * 2], wb = wrow[h8 * 2 + 1];
      const int h = h8 * 8;
      #pragma unroll
      for (int r = 0; r < 8; ++r){
        const float* xr = &ds[r][h];
        ll[r] += xr[0]*wa.x + xr[1]*wa.y + xr[2]*wa.z + xr[3]*wa.w
               + xr[4]*wb.x + xr[5]*wb.y + xr[6]*wb.z + xr[7]*wb.w;
      }
    }
    const float bv = wvb[j];
    #pragma unroll
    for (int r = 0; r < 8; ++r) ll[r] += sv[row0 + r] * bv;
  }
  #pragma unroll
  for (int r = 0; r < 8; ++r) ys[r][j] = ll[r];
  __syncthreads();

  {
    float a[8];
    #pragma unroll
    for (int r = 0; r < 8; ++r) a[r] = 0.f;
    const float4* wrow = (const float4*)(f1 + (long)j * 256);
    for (int h8 = 0; h8 < 32; ++h8){
      float4 wa = wrow[h8 * 2], wb = wrow[h8 * 2 + 1];
      const int h = h8 * 8;
      #pragma unroll
      for (int r = 0; r < 8; ++r){
        const float* xr = &ys[r][h];
        a[r] += xr[0]*wa.x + xr[1]*wa.y + xr[2]*wa.z + xr[3]*wa.w
              + xr[4]*wb.x + xr[5]*wb.y + xr[6]*wb.z + xr[7]*wb.w;
      }
    }
    const float b1 = f1b[j];
    #pragma unroll
    for (int r = 0; r < 8; ++r){
      const float x = a[r] + b1;
      ds[r][j] = (x > 0.f) ? x : expm1f(x);   // jax.nn.elu
    }
  }
  __syncthreads();

  float xv[8];
  {
    float a[8];
    #pragma unroll
    for (int r = 0; r < 8; ++r) a[r] = 0.f;
    const float4* wrow = (const float4*)(f2 + (long)j * 256);
    for (int h8 = 0; h8 < 32; ++h8){
      float4 wa = wrow[h8 * 2], wb = wrow[h8 * 2 + 1];
      const int h = h8 * 8;
      #pragma unroll
      for (int r = 0; r < 8; ++r){
        const float* xr = &ds[r][h];
        a[r] += xr[0]*wa.x + xr[1]*wa.y + xr[2]*wa.z + xr[3]*wa.w
              + xr[4]*wb.x + xr[5]*wb.y + xr[6]*wb.z + xr[7]*wb.w;
      }
    }
    const float b2_ = f2b[j];
    #pragma unroll
    for (int r = 0; r < 8; ++r) xv[r] = ll[r] + a[r] + b2_;
  }
  #pragma unroll
  for (int r = 0; r < 8; ++r) ys[r][j] = xv[r];
  __syncthreads();

  {
    const int lane = j & 63, wvi = j >> 6;
    for (int rr = 0; rr < 2; ++rr){
      const int r = wvi * 2 + rr;
      float s = 0.f, qq = 0.f;
      for (int p = lane; p < 256; p += 64){ const float x = ys[r][p]; s += x; qq += x * x; }
      #pragma unroll
      for (int off = 32; off; off >>= 1){ s += __shfl_xor(s, off); qq += __shfl_xor(qq, off); }
      if (lane == 0){
        const float mu = s * (1.f/256.f);
        const float var = qq * (1.f/256.f) - mu * mu;
        mu_s[r] = mu; rs_s[r] = rsqrtf(var + 1e-5f);
      }
    }
  }
  __syncthreads();
  const float gj = lng[j], bj = lnb[j];
  #pragma unroll
  for (int r = 0; r < 8; ++r){
    const float o = (ys[r][j] - mu_s[r]) * rs_s[r] * gj + bj;
    out[(long)(row0 + r) * 256 + j] = o;
  }
}

extern "C" void kernel_launch(void* const* d_in, const int* in_sizes, int n_in,
                              void* d_out, int out_size, void* d_ws, size_t ws_size,
                              hipStream_t stream)
{
  (void)in_sizes; (void)n_in; (void)out_size; (void)ws_size;
  const float* target_h = (const float*)d_in[0];
  const float* peer_h   = (const float*)d_in[1];
  const float* wq_w = (const float*)d_in[2];  const float* wq_b = (const float*)d_in[3];
  const float* wk_w = (const float*)d_in[4];  const float* wk_b = (const float*)d_in[5];
  const float* wv_w = (const float*)d_in[6];  const float* wv_b = (const float*)d_in[7];
  const float* f1_w = (const float*)d_in[8];  const float* f1_b = (const float*)d_in[9];
  const float* f2_w = (const float*)d_in[10]; const float* f2_b = (const float*)d_in[11];
  const float* ln_g = (const float*)d_in[12]; const float* ln_b = (const float*)d_in[13];
  const float* alpha = (const float*)d_in[14];
  const float* lrs  = (const float*)d_in[15];
  const void* pmask = d_in[16];
  const void* rmask = d_in[17];
  const int* target_id = (const int*)d_in[18];
  const int* peer_id   = (const int*)d_in[19];

  // ws layout (f32): prior[4*192] | Qt[1536*256] | qb[1536] | d[1536*256] | s[1536]
  float* prior = (float*)d_ws;
  float* Qt    = prior + 4 * 192;
  float* qb    = Qt + 393216;
  float* dvec  = qb + 1536;
  float* ssum  = dvec + 393216;

  qproj_prep_kernel<<<196, 256, 0, stream>>>(target_h, wq_w, wq_b, wk_w, wk_b,
      lrs, pmask, rmask, target_id, peer_id, alpha, Qt, qb, prior);
  attn_kernel<<<1536, 256, 0, stream>>>(peer_h, Qt, qb, prior, dvec, ssum);
  ffn_kernel<<<192, 256, 0, stream>>>(dvec, ssum, wv_w, wv_b, f1_w, f1_b,
                                      f2_w, f2_b, ln_g, ln_b, (float*)d_out);
}